// Round 1
// baseline (1751.611 us; speedup 1.0000x reference)
//
#include <hip/hip_runtime.h>

typedef __bf16 bf16;
typedef bf16 bf16x8 __attribute__((ext_vector_type(8)));
typedef bf16 bf16x4 __attribute__((ext_vector_type(4)));
typedef float floatx4 __attribute__((ext_vector_type(4)));

#define HID 2048
#define MROWS 4096   // B*S

// ---------------- f32 -> bf16 convert ----------------
__global__ __launch_bounds__(256) void convert_bf16_kernel(const float* __restrict__ X, bf16* __restrict__ Y)
{
    const int i = (blockIdx.x * 256 + threadIdx.x) * 4;
    const float4 v = *(const float4*)(X + i);
    bf16x4 o;
    o[0] = (bf16)v.x; o[1] = (bf16)v.y; o[2] = (bf16)v.z; o[3] = (bf16)v.w;
    *(bf16x4*)(Y + i) = o;
}

// ---------------- W f32 [K][N] -> W^T bf16 [N][K] ----------------
__global__ __launch_bounds__(256) void transpose_convert_kernel(const float* __restrict__ W, bf16* __restrict__ WT)
{
    __shared__ float tile[32][33];
    const int n0 = blockIdx.x * 32, k0 = blockIdx.y * 32;
    const int tx = threadIdx.x & 31, ty = threadIdx.x >> 5;
    #pragma unroll
    for (int r = 0; r < 32; r += 8)
        tile[ty + r][tx] = W[(size_t)(k0 + ty + r) * HID + n0 + tx];
    __syncthreads();
    #pragma unroll
    for (int r = 0; r < 32; r += 8)
        WT[(size_t)(n0 + ty + r) * HID + k0 + tx] = (bf16)tile[tx][ty + r];
}

// ---------------- bf16 MFMA GEMM: C[M][N] = A[M][K] @ BT[N][K]^T + bias ----------------
// Verified gfx950 16x16x32 bf16 fragment layout:
//   A-frag: lane holds A[m=lane&15][k=(lane>>4)*8 + j]
//   B-frag: lane holds B[k=(lane>>4)*8+j][n=lane&15] == BT[n=lane&15][k]
//   C/D   : col=lane&15, row=(lane>>4)*4 + reg
template<bool SIGMOID>
__global__ __launch_bounds__(256) void gemm_bt_kernel(const bf16* __restrict__ A, const bf16* __restrict__ BT,
                                                      const float* __restrict__ bias, bf16* __restrict__ C)
{
    constexpr int LDK = 72;  // 64 + 8 pad: keeps ds_read_b128 2-way (free), 16B-aligned
    __shared__ __align__(16) bf16 As[128 * LDK];
    __shared__ __align__(16) bf16 Bs[128 * LDK];
    const int tid = threadIdx.x;
    const int wave = tid >> 6, lane = tid & 63;
    const int m0 = blockIdx.x * 128, n0 = blockIdx.y * 128;
    const int wm = (wave & 1) * 64, wn = (wave >> 1) * 64;
    const int l15 = lane & 15, q = lane >> 4;
    floatx4 acc[4][4] = {};

    const int srow = tid >> 3;         // 0..31 per round
    const int scol = (tid & 7) * 8;    // 0..56

    for (int kt = 0; kt < HID; kt += 64) {
        __syncthreads();
        #pragma unroll
        for (int rr = 0; rr < 4; rr++) {
            const int row = rr * 32 + srow;
            const bf16x8 av = *(const bf16x8*)(A  + (size_t)(m0 + row) * HID + kt + scol);
            *(bf16x8*)(As + row * LDK + scol) = av;
            const bf16x8 bv = *(const bf16x8*)(BT + (size_t)(n0 + row) * HID + kt + scol);
            *(bf16x8*)(Bs + row * LDK + scol) = bv;
        }
        __syncthreads();
        #pragma unroll
        for (int ks = 0; ks < 2; ks++) {
            const int kk = ks * 32 + q * 8;
            bf16x8 af[4], bfr[4];
            #pragma unroll
            for (int i = 0; i < 4; i++)
                af[i] = *(const bf16x8*)(As + (wm + i * 16 + l15) * LDK + kk);
            #pragma unroll
            for (int j = 0; j < 4; j++)
                bfr[j] = *(const bf16x8*)(Bs + (wn + j * 16 + l15) * LDK + kk);
            #pragma unroll
            for (int i = 0; i < 4; i++)
                #pragma unroll
                for (int j = 0; j < 4; j++)
                    acc[i][j] = __builtin_amdgcn_mfma_f32_16x16x32_bf16(af[i], bfr[j], acc[i][j], 0, 0, 0);
        }
    }
    #pragma unroll
    for (int j = 0; j < 4; j++) {
        const int col = n0 + wn + j * 16 + l15;
        const float bv = bias[col];
        #pragma unroll
        for (int i = 0; i < 4; i++) {
            #pragma unroll
            for (int r = 0; r < 4; r++) {
                const int row = m0 + wm + i * 16 + q * 4 + r;
                float val = acc[i][j][r] + bv;
                if (SIGMOID) val = 1.0f / (1.0f + __expf(-val));
                C[(size_t)row * HID + col] = (bf16)val;
            }
        }
    }
}

// ---------------- flash-style attention, fp32 vector math, bf16 storage ----------------
// grid: (B*NH=32, S/64=32), block 256. Per block: 64 queries of one head.
__global__ __launch_bounds__(256) void attention_kernel(const bf16* __restrict__ Q, const bf16* __restrict__ K,
                                                        const bf16* __restrict__ V, bf16* __restrict__ O)
{
    constexpr int AP = 136;  // 128 + 8 pad (bf16)
    constexpr int PP = 68;   // 64 + 4 pad (f32)
    __shared__ __align__(16) bf16 Qs[64 * AP];
    __shared__ __align__(16) bf16 Ks[64 * AP];
    __shared__ __align__(16) bf16 Vs[64 * AP];
    __shared__ __align__(16) float Ps[64 * PP];

    const int tid = threadIdx.x;
    const int b = blockIdx.x >> 4, h = blockIdx.x & 15;
    const int q0 = blockIdx.y * 64;
    const size_t rs = HID;
    const bf16* Qg = Q + ((size_t)b * 2048 + q0) * rs + h * 128;
    const bf16* Kg = K + (size_t)b * 2048 * rs + h * 128;
    const bf16* Vg = V + (size_t)b * 2048 * rs + h * 128;

    const int strow = tid >> 4;        // staging: 16 rows/round
    const int std8  = (tid & 15) * 8;
    #pragma unroll
    for (int rr = 0; rr < 4; rr++) {
        const int row = rr * 16 + strow;
        *(bf16x8*)(Qs + row * AP + std8) = *(const bf16x8*)(Qg + (size_t)row * rs + std8);
    }
    const int qg = tid >> 4;   // row group: rows qg*4..+3 (same partition for scores & PV)
    const int kg = tid & 15;   // scores: keys kg*4..+3 ; PV: dims kg*8..+7
    float m_st[4], l_st[4], Oacc[4][8];
    #pragma unroll
    for (int r = 0; r < 4; r++) {
        m_st[r] = -1e30f; l_st[r] = 0.f;
        #pragma unroll
        for (int e = 0; e < 8; e++) Oacc[r][e] = 0.f;
    }
    const float scale = 0.08838834764831845f;  // 1/sqrt(128)

    for (int kt = 0; kt < 2048; kt += 64) {
        __syncthreads();
        #pragma unroll
        for (int rr = 0; rr < 4; rr++) {
            const int row = rr * 16 + strow;
            *(bf16x8*)(Ks + row * AP + std8) = *(const bf16x8*)(Kg + (size_t)(kt + row) * rs + std8);
            *(bf16x8*)(Vs + row * AP + std8) = *(const bf16x8*)(Vg + (size_t)(kt + row) * rs + std8);
        }
        __syncthreads();
        // --- scores: s[r][c] = Q[qg*4+r] . K[kg*4+c] ---
        float s[4][4] = {};
        #pragma unroll 2
        for (int dc = 0; dc < 128; dc += 8) {
            float qf[4][8], kf[4][8];
            #pragma unroll
            for (int r = 0; r < 4; r++) {
                const bf16x8 qv = *(const bf16x8*)(Qs + (qg * 4 + r) * AP + dc);
                #pragma unroll
                for (int e = 0; e < 8; e++) qf[r][e] = (float)qv[e];
            }
            #pragma unroll
            for (int c = 0; c < 4; c++) {
                const bf16x8 kv = *(const bf16x8*)(Ks + (kg * 4 + c) * AP + dc);
                #pragma unroll
                for (int e = 0; e < 8; e++) kf[c][e] = (float)kv[e];
            }
            #pragma unroll
            for (int r = 0; r < 4; r++)
                #pragma unroll
                for (int c = 0; c < 4; c++)
                    #pragma unroll
                    for (int e = 0; e < 8; e++)
                        s[r][c] += qf[r][e] * kf[c][e];
        }
        // --- online softmax (16 lanes of a row group hold that row's 64 scores) ---
        #pragma unroll
        for (int r = 0; r < 4; r++) {
            float mx = -1e30f;
            #pragma unroll
            for (int c = 0; c < 4; c++) { s[r][c] *= scale; mx = fmaxf(mx, s[r][c]); }
            #pragma unroll
            for (int o = 1; o < 16; o <<= 1) mx = fmaxf(mx, __shfl_xor(mx, o));
            const float nm = fmaxf(m_st[r], mx);
            float pr[4], ps = 0.f;
            #pragma unroll
            for (int c = 0; c < 4; c++) { pr[c] = __expf(s[r][c] - nm); ps += pr[c]; }
            #pragma unroll
            for (int o = 1; o < 16; o <<= 1) ps += __shfl_xor(ps, o);
            const float alpha = __expf(m_st[r] - nm);
            l_st[r] = l_st[r] * alpha + ps;
            m_st[r] = nm;
            #pragma unroll
            for (int e = 0; e < 8; e++) Oacc[r][e] *= alpha;
            *(float4*)(Ps + (qg * 4 + r) * PP + kg * 4) = make_float4(pr[0], pr[1], pr[2], pr[3]);
        }
        __syncthreads();
        // --- PV: Oacc[r][dims kg*8..+7] += P[row][kj] * V[kj][dim] ---
        #pragma unroll 4
        for (int kjb = 0; kjb < 16; kjb++) {
            float4 p4[4];
            #pragma unroll
            for (int r = 0; r < 4; r++) p4[r] = *(const float4*)(Ps + (qg * 4 + r) * PP + kjb * 4);
            #pragma unroll
            for (int kk = 0; kk < 4; kk++) {
                const bf16x8 vv = *(const bf16x8*)(Vs + (kjb * 4 + kk) * AP + kg * 8);
                float vf[8];
                #pragma unroll
                for (int e = 0; e < 8; e++) vf[e] = (float)vv[e];
                #pragma unroll
                for (int r = 0; r < 4; r++) {
                    const float pv = (kk == 0) ? p4[r].x : (kk == 1) ? p4[r].y : (kk == 2) ? p4[r].z : p4[r].w;
                    #pragma unroll
                    for (int e = 0; e < 8; e++) Oacc[r][e] += pv * vf[e];
                }
            }
        }
    }
    #pragma unroll
    for (int r = 0; r < 4; r++) {
        const float inv = 1.0f / l_st[r];
        bf16x8 ov;
        #pragma unroll
        for (int e = 0; e < 8; e++) ov[e] = (bf16)(Oacc[r][e] * inv);
        *(bf16x8*)(O + ((size_t)b * 2048 + q0 + qg * 4 + r) * rs + h * 128 + kg * 8) = ov;
    }
}

// ---------------- residual + gate + LayerNorm ----------------
__global__ __launch_bounds__(256) void ln_kernel(const float* __restrict__ hidden, const bf16* __restrict__ gate,
                                                 const bf16* __restrict__ attnp, const float* __restrict__ gamma,
                                                 const float* __restrict__ beta, float* __restrict__ out)
{
    __shared__ float red[4];
    __shared__ float red2[4];
    const int row = blockIdx.x;
    const int tid = threadIdx.x;
    const size_t base = (size_t)row * HID;
    const int c0 = tid * 8;
    const float4 h0 = *(const float4*)(hidden + base + c0);
    const float4 h1 = *(const float4*)(hidden + base + c0 + 4);
    const bf16x8 g = *(const bf16x8*)(gate + base + c0);
    const bf16x8 a = *(const bf16x8*)(attnp + base + c0);
    float t[8] = {h0.x, h0.y, h0.z, h0.w, h1.x, h1.y, h1.z, h1.w};
    float sum = 0.f;
    #pragma unroll
    for (int e = 0; e < 8; e++) { t[e] += (float)g[e] * (float)a[e]; sum += t[e]; }
    #pragma unroll
    for (int o = 1; o < 64; o <<= 1) sum += __shfl_xor(sum, o);
    const int wave = tid >> 6, lane = tid & 63;
    if (lane == 0) red[wave] = sum;
    __syncthreads();
    const float mu = (red[0] + red[1] + red[2] + red[3]) * (1.f / HID);
    float vs = 0.f;
    #pragma unroll
    for (int e = 0; e < 8; e++) { const float d = t[e] - mu; vs += d * d; }
    #pragma unroll
    for (int o = 1; o < 64; o <<= 1) vs += __shfl_xor(vs, o);
    if (lane == 0) red2[wave] = vs;
    __syncthreads();
    const float var = (red2[0] + red2[1] + red2[2] + red2[3]) * (1.f / HID);
    const float inv = rsqrtf(var + 1e-5f);
    float res[8];
    #pragma unroll
    for (int e = 0; e < 8; e++) res[e] = (t[e] - mu) * inv * gamma[c0 + e] + beta[c0 + e];
    *(float4*)(out + base + c0)     = make_float4(res[0], res[1], res[2], res[3]);
    *(float4*)(out + base + c0 + 4) = make_float4(res[4], res[5], res[6], res[7]);
}

extern "C" void kernel_launch(void* const* d_in, const int* in_sizes, int n_in,
                              void* d_out, int out_size, void* d_ws, size_t ws_size,
                              hipStream_t stream) {
    const float* hidden = (const float*)d_in[0];
    const float* cross  = (const float*)d_in[1];
    const float* Wq = (const float*)d_in[2];
    const float* bq = (const float*)d_in[3];
    const float* Wk = (const float*)d_in[4];
    const float* bk = (const float*)d_in[5];
    const float* Wv = (const float*)d_in[6];
    const float* bv = (const float*)d_in[7];
    const float* Wo = (const float*)d_in[8];
    const float* bo = (const float*)d_in[9];
    const float* Wg = (const float*)d_in[10];
    const float* bg = (const float*)d_in[11];
    const float* gamma = (const float*)d_in[12];
    const float* beta  = (const float*)d_in[13];
    float* out = (float*)d_out;

    char* ws = (char*)d_ws;
    const size_t MB = 1ull << 20;
    bf16* hbf = (bf16*)(ws);             // 16 MB  hidden bf16
    bf16* cbf = (bf16*)(ws + 16 * MB);   // 16 MB  cross bf16
    bf16* WqT = (bf16*)(ws + 32 * MB);   // 8 MB each, transposed bf16 weights
    bf16* WkT = (bf16*)(ws + 40 * MB);
    bf16* WvT = (bf16*)(ws + 48 * MB);
    bf16* WoT = (bf16*)(ws + 56 * MB);
    bf16* WgT = (bf16*)(ws + 64 * MB);
    bf16* qbf = (bf16*)(ws + 72 * MB);   // 16 MB
    bf16* kbf = (bf16*)(ws + 88 * MB);   // 16 MB
    bf16* vbf = (bf16*)(ws + 104 * MB);  // 16 MB
    bf16* gbf = (bf16*)(ws + 120 * MB);  // 16 MB  sigmoid gate
    bf16* abf = (bf16*)(ws + 136 * MB);  // 16 MB  attention out (pre-Wo)
    bf16* pbf = qbf;                     // attn @ Wo + bo, reuses q slot (q dead by then)

    convert_bf16_kernel<<<8192, 256, 0, stream>>>(hidden, hbf);
    convert_bf16_kernel<<<8192, 256, 0, stream>>>(cross, cbf);
    const dim3 tg(64, 64);
    transpose_convert_kernel<<<tg, 256, 0, stream>>>(Wq, WqT);
    transpose_convert_kernel<<<tg, 256, 0, stream>>>(Wk, WkT);
    transpose_convert_kernel<<<tg, 256, 0, stream>>>(Wv, WvT);
    transpose_convert_kernel<<<tg, 256, 0, stream>>>(Wo, WoT);
    transpose_convert_kernel<<<tg, 256, 0, stream>>>(Wg, WgT);
    const dim3 gg(MROWS / 128, HID / 128);   // 32 x 16
    gemm_bt_kernel<false><<<gg, 256, 0, stream>>>(hbf, WqT, bq, qbf);
    gemm_bt_kernel<false><<<gg, 256, 0, stream>>>(cbf, WkT, bk, kbf);
    gemm_bt_kernel<false><<<gg, 256, 0, stream>>>(cbf, WvT, bv, vbf);
    gemm_bt_kernel<true ><<<gg, 256, 0, stream>>>(hbf, WgT, bg, gbf);
    attention_kernel<<<dim3(32, 32), 256, 0, stream>>>(qbf, kbf, vbf, abf);
    gemm_bt_kernel<false><<<gg, 256, 0, stream>>>(abf, WoT, bo, pbf);
    ln_kernel<<<MROWS, 256, 0, stream>>>(hidden, gbf, pbf, gamma, beta, out);
}

// Round 2
// 634.907 us; speedup vs baseline: 2.7588x; 2.7588x over previous
//
#include <hip/hip_runtime.h>

typedef __bf16 bf16;
typedef bf16 bf16x8 __attribute__((ext_vector_type(8)));
typedef bf16 bf16x4 __attribute__((ext_vector_type(4)));
typedef float floatx4 __attribute__((ext_vector_type(4)));

#define HID 2048
#define MROWS 4096   // B*S

// ---------------- f32 -> bf16 convert ----------------
__global__ __launch_bounds__(256) void convert_bf16_kernel(const float* __restrict__ X, bf16* __restrict__ Y)
{
    const int i = (blockIdx.x * 256 + threadIdx.x) * 4;
    const float4 v = *(const float4*)(X + i);
    bf16x4 o;
    o[0] = (bf16)v.x; o[1] = (bf16)v.y; o[2] = (bf16)v.z; o[3] = (bf16)v.w;
    *(bf16x4*)(Y + i) = o;
}

// ---------------- W f32 [K][N] -> W^T bf16 [N][K] ----------------
__global__ __launch_bounds__(256) void transpose_convert_kernel(const float* __restrict__ W, bf16* __restrict__ WT)
{
    __shared__ float tile[32][33];
    const int n0 = blockIdx.x * 32, k0 = blockIdx.y * 32;
    const int tx = threadIdx.x & 31, ty = threadIdx.x >> 5;
    #pragma unroll
    for (int r = 0; r < 32; r += 8)
        tile[ty + r][tx] = W[(size_t)(k0 + ty + r) * HID + n0 + tx];
    __syncthreads();
    #pragma unroll
    for (int r = 0; r < 32; r += 8)
        WT[(size_t)(n0 + ty + r) * HID + k0 + tx] = (bf16)tile[tx][ty + r];
}

// ---------------- bf16 [t][c] -> bf16 [c][t] per batch (for V) ----------------
__global__ __launch_bounds__(256) void transpose_v_kernel(const bf16* __restrict__ X, bf16* __restrict__ Y)
{
    __shared__ bf16 tile[32][33];
    const int b = blockIdx.z;
    const int c0 = blockIdx.x * 32, t0 = blockIdx.y * 32;
    const int tx = threadIdx.x & 31, ty = threadIdx.x >> 5;
    const bf16* Xb = X + (size_t)b * HID * HID;
    bf16* Yb = Y + (size_t)b * HID * HID;
    #pragma unroll
    for (int r = 0; r < 32; r += 8)
        tile[ty + r][tx] = Xb[(size_t)(t0 + ty + r) * HID + c0 + tx];
    __syncthreads();
    #pragma unroll
    for (int r = 0; r < 32; r += 8)
        Yb[(size_t)(c0 + ty + r) * HID + t0 + tx] = tile[tx][ty + r];
}

// ---------------- bf16 MFMA GEMM: C[M][N] = A[M][K] @ BT[N][K]^T + bias ----------------
// Verified gfx950 16x16x32 bf16 fragment layout:
//   A-frag: lane holds A[m=lane&15][k=(lane>>4)*8 + j]
//   B-frag: lane holds B[k=(lane>>4)*8+j][n=lane&15] == BT[n=lane&15][k]
//   C/D   : col=lane&15, row=(lane>>4)*4 + reg
template<bool SIGMOID>
__global__ __launch_bounds__(256) void gemm_bt_kernel(const bf16* __restrict__ A, const bf16* __restrict__ BT,
                                                      const float* __restrict__ bias, bf16* __restrict__ C)
{
    constexpr int LDK = 72;  // 64 + 8 pad: keeps ds_read_b128 2-way (free), 16B-aligned
    __shared__ __align__(16) bf16 As[128 * LDK];
    __shared__ __align__(16) bf16 Bs[128 * LDK];
    const int tid = threadIdx.x;
    const int wave = tid >> 6, lane = tid & 63;
    const int m0 = blockIdx.x * 128, n0 = blockIdx.y * 128;
    const int wm = (wave & 1) * 64, wn = (wave >> 1) * 64;
    const int l15 = lane & 15, q = lane >> 4;
    floatx4 acc[4][4] = {};

    const int srow = tid >> 3;         // 0..31 per round
    const int scol = (tid & 7) * 8;    // 0..56

    for (int kt = 0; kt < HID; kt += 64) {
        __syncthreads();
        #pragma unroll
        for (int rr = 0; rr < 4; rr++) {
            const int row = rr * 32 + srow;
            const bf16x8 av = *(const bf16x8*)(A  + (size_t)(m0 + row) * HID + kt + scol);
            *(bf16x8*)(As + row * LDK + scol) = av;
            const bf16x8 bv = *(const bf16x8*)(BT + (size_t)(n0 + row) * HID + kt + scol);
            *(bf16x8*)(Bs + row * LDK + scol) = bv;
        }
        __syncthreads();
        #pragma unroll
        for (int ks = 0; ks < 2; ks++) {
            const int kk = ks * 32 + q * 8;
            bf16x8 af[4], bfr[4];
            #pragma unroll
            for (int i = 0; i < 4; i++)
                af[i] = *(const bf16x8*)(As + (wm + i * 16 + l15) * LDK + kk);
            #pragma unroll
            for (int j = 0; j < 4; j++)
                bfr[j] = *(const bf16x8*)(Bs + (wn + j * 16 + l15) * LDK + kk);
            #pragma unroll
            for (int i = 0; i < 4; i++)
                #pragma unroll
                for (int j = 0; j < 4; j++)
                    acc[i][j] = __builtin_amdgcn_mfma_f32_16x16x32_bf16(af[i], bfr[j], acc[i][j], 0, 0, 0);
        }
    }
    #pragma unroll
    for (int j = 0; j < 4; j++) {
        const int col = n0 + wn + j * 16 + l15;
        const float bv = bias[col];
        #pragma unroll
        for (int i = 0; i < 4; i++) {
            #pragma unroll
            for (int r = 0; r < 4; r++) {
                const int row = m0 + wm + i * 16 + q * 4 + r;
                float val = acc[i][j][r] + bv;
                if (SIGMOID) val = 1.0f / (1.0f + __expf(-val));
                C[(size_t)row * HID + col] = (bf16)val;
            }
        }
    }
}

// ---------------- MFMA flash attention ----------------
// grid: (B*NH=32, S/64=32), block 256 (4 waves). Per block: 64 queries of one head.
// Q,K: [b*2048+t][h*128+d] bf16 (k-contiguous for A/B frags).
// Vt:  [b*2048 + h*128+d][t] bf16 (so PV B-frags are k(=key)-contiguous).
__global__ __launch_bounds__(256) void attention_mfma_kernel(const bf16* __restrict__ Q, const bf16* __restrict__ K,
                                                             const bf16* __restrict__ Vt, bf16* __restrict__ O)
{
    constexpr int QP = 136, KP = 136, VP = 72, PP = 72;  // pitches (bf16) with pad -> <=2-way banks
    __shared__ __align__(16) bf16 Qs[64 * QP];
    __shared__ __align__(16) bf16 Ks[64 * KP];
    __shared__ __align__(16) bf16 Vts[128 * VP];
    __shared__ __align__(16) bf16 Ps[64 * PP];

    const int tid = threadIdx.x;
    const int wave = tid >> 6, lane = tid & 63;
    const int l15 = lane & 15, quad = lane >> 4;
    const int b = blockIdx.x >> 4, h = blockIdx.x & 15;
    const int q0 = blockIdx.y * 64;
    const bf16* Qg = Q + (size_t)(b * 2048 + q0) * HID + h * 128;
    const bf16* Kg = K + (size_t)b * 2048 * HID + h * 128;
    const bf16* Vg = Vt + (size_t)(b * 2048 + h * 128) * HID;  // rows=dim, cols=token

    // stage Q tile (64 x 128)
    #pragma unroll
    for (int rr = 0; rr < 4; rr++) {
        const int c = rr * 256 + tid;
        const int row = c >> 4, col8 = (c & 15) * 8;
        *(bf16x8*)(Qs + row * QP + col8) = *(const bf16x8*)(Qg + (size_t)row * HID + col8);
    }

    const int wq0 = wave * 16;               // this wave's 16 query rows
    const float scale = 0.08838834764831845f; // 1/sqrt(128)
    float m_st[4], l_st[4];
    floatx4 oacc[8];
    #pragma unroll
    for (int r = 0; r < 4; r++) { m_st[r] = -1e30f; l_st[r] = 0.f; }
    #pragma unroll
    for (int dt = 0; dt < 8; dt++) oacc[dt] = (floatx4){0.f, 0.f, 0.f, 0.f};

    for (int kt = 0; kt < 2048; kt += 64) {
        __syncthreads();
        // stage K tile (64 keys x 128 dims) and Vt tile (128 dims x 64 keys)
        #pragma unroll
        for (int rr = 0; rr < 4; rr++) {
            const int c = rr * 256 + tid;
            const int row = c >> 4, col8 = (c & 15) * 8;
            *(bf16x8*)(Ks + row * KP + col8) = *(const bf16x8*)(Kg + (size_t)(kt + row) * HID + col8);
        }
        #pragma unroll
        for (int rr = 0; rr < 4; rr++) {
            const int c = rr * 256 + tid;
            const int row = c >> 3, col8 = (c & 7) * 8;
            *(bf16x8*)(Vts + row * VP + col8) = *(const bf16x8*)(Vg + (size_t)row * HID + kt + col8);
        }
        __syncthreads();

        // S = Q K^T : 16 rows x 64 keys per wave, C-layout
        floatx4 sacc[4] = {};
        #pragma unroll
        for (int kk = 0; kk < 4; kk++) {
            const bf16x8 af = *(const bf16x8*)(Qs + (wq0 + l15) * QP + kk * 32 + quad * 8);
            #pragma unroll
            for (int j = 0; j < 4; j++) {
                const bf16x8 bfr = *(const bf16x8*)(Ks + (j * 16 + l15) * KP + kk * 32 + quad * 8);
                sacc[j] = __builtin_amdgcn_mfma_f32_16x16x32_bf16(af, bfr, sacc[j], 0, 0, 0);
            }
        }

        // online softmax: lane owns rows quad*4+r, cols j*16+l15
        #pragma unroll
        for (int r = 0; r < 4; r++) {
            float s[4];
            float mx = -1e30f;
            #pragma unroll
            for (int j = 0; j < 4; j++) { s[j] = sacc[j][r] * scale; mx = fmaxf(mx, s[j]); }
            #pragma unroll
            for (int o = 1; o < 16; o <<= 1) mx = fmaxf(mx, __shfl_xor(mx, o));
            const float nm = fmaxf(m_st[r], mx);
            float p[4], ps = 0.f;
            #pragma unroll
            for (int j = 0; j < 4; j++) { p[j] = __expf(s[j] - nm); ps += p[j]; }
            #pragma unroll
            for (int o = 1; o < 16; o <<= 1) ps += __shfl_xor(ps, o);
            const float alpha = __expf(m_st[r] - nm);
            l_st[r] = l_st[r] * alpha + ps;
            m_st[r] = nm;
            #pragma unroll
            for (int dt = 0; dt < 8; dt++) oacc[dt][r] *= alpha;
            const int prow = wq0 + quad * 4 + r;
            #pragma unroll
            for (int j = 0; j < 4; j++)
                Ps[prow * PP + j * 16 + l15] = (bf16)p[j];
        }
        __syncthreads();

        // O += P V : P as A-frags from LDS, Vt as B-frags
        #pragma unroll
        for (int ks = 0; ks < 2; ks++) {
            const bf16x8 af = *(const bf16x8*)(Ps + (wq0 + l15) * PP + ks * 32 + quad * 8);
            #pragma unroll
            for (int dt = 0; dt < 8; dt++) {
                const bf16x8 bfr = *(const bf16x8*)(Vts + (dt * 16 + l15) * VP + ks * 32 + quad * 8);
                oacc[dt] = __builtin_amdgcn_mfma_f32_16x16x32_bf16(af, bfr, oacc[dt], 0, 0, 0);
            }
        }
    }

    // write O (divide by l), C-layout: row=quad*4+r, col=dt*16+l15
    #pragma unroll
    for (int r = 0; r < 4; r++) {
        const float inv = 1.0f / l_st[r];
        const size_t row = (size_t)(b * 2048 + q0 + wq0 + quad * 4 + r);
        #pragma unroll
        for (int dt = 0; dt < 8; dt++)
            O[row * HID + h * 128 + dt * 16 + l15] = (bf16)(oacc[dt][r] * inv);
    }
}

// ---------------- residual + gate + LayerNorm ----------------
__global__ __launch_bounds__(256) void ln_kernel(const float* __restrict__ hidden, const bf16* __restrict__ gate,
                                                 const bf16* __restrict__ attnp, const float* __restrict__ gamma,
                                                 const float* __restrict__ beta, float* __restrict__ out)
{
    __shared__ float red[4];
    __shared__ float red2[4];
    const int row = blockIdx.x;
    const int tid = threadIdx.x;
    const size_t base = (size_t)row * HID;
    const int c0 = tid * 8;
    const float4 h0 = *(const float4*)(hidden + base + c0);
    const float4 h1 = *(const float4*)(hidden + base + c0 + 4);
    const bf16x8 g = *(const bf16x8*)(gate + base + c0);
    const bf16x8 a = *(const bf16x8*)(attnp + base + c0);
    float t[8] = {h0.x, h0.y, h0.z, h0.w, h1.x, h1.y, h1.z, h1.w};
    float sum = 0.f;
    #pragma unroll
    for (int e = 0; e < 8; e++) { t[e] += (float)g[e] * (float)a[e]; sum += t[e]; }
    #pragma unroll
    for (int o = 1; o < 64; o <<= 1) sum += __shfl_xor(sum, o);
    const int wave = tid >> 6, lane = tid & 63;
    if (lane == 0) red[wave] = sum;
    __syncthreads();
    const float mu = (red[0] + red[1] + red[2] + red[3]) * (1.f / HID);
    float vs = 0.f;
    #pragma unroll
    for (int e = 0; e < 8; e++) { const float d = t[e] - mu; vs += d * d; }
    #pragma unroll
    for (int o = 1; o < 64; o <<= 1) vs += __shfl_xor(vs, o);
    if (lane == 0) red2[wave] = vs;
    __syncthreads();
    const float var = (red2[0] + red2[1] + red2[2] + red2[3]) * (1.f / HID);
    const float inv = rsqrtf(var + 1e-5f);
    float res[8];
    #pragma unroll
    for (int e = 0; e < 8; e++) res[e] = (t[e] - mu) * inv * gamma[c0 + e] + beta[c0 + e];
    *(float4*)(out + base + c0)     = make_float4(res[0], res[1], res[2], res[3]);
    *(float4*)(out + base + c0 + 4) = make_float4(res[4], res[5], res[6], res[7]);
}

extern "C" void kernel_launch(void* const* d_in, const int* in_sizes, int n_in,
                              void* d_out, int out_size, void* d_ws, size_t ws_size,
                              hipStream_t stream) {
    const float* hidden = (const float*)d_in[0];
    const float* cross  = (const float*)d_in[1];
    const float* Wq = (const float*)d_in[2];
    const float* bq = (const float*)d_in[3];
    const float* Wk = (const float*)d_in[4];
    const float* bk = (const float*)d_in[5];
    const float* Wv = (const float*)d_in[6];
    const float* bv = (const float*)d_in[7];
    const float* Wo = (const float*)d_in[8];
    const float* bo = (const float*)d_in[9];
    const float* Wg = (const float*)d_in[10];
    const float* bg = (const float*)d_in[11];
    const float* gamma = (const float*)d_in[12];
    const float* beta  = (const float*)d_in[13];
    float* out = (float*)d_out;

    char* ws = (char*)d_ws;
    const size_t MB = 1ull << 20;
    bf16* hbf = (bf16*)(ws);             // 16 MB  hidden bf16
    bf16* cbf = (bf16*)(ws + 16 * MB);   // 16 MB  cross bf16 (reused as Vt after V GEMM)
    bf16* WqT = (bf16*)(ws + 32 * MB);   // 8 MB each, transposed bf16 weights
    bf16* WkT = (bf16*)(ws + 40 * MB);
    bf16* WvT = (bf16*)(ws + 48 * MB);
    bf16* WoT = (bf16*)(ws + 56 * MB);
    bf16* WgT = (bf16*)(ws + 64 * MB);
    bf16* qbf = (bf16*)(ws + 72 * MB);   // 16 MB
    bf16* kbf = (bf16*)(ws + 88 * MB);   // 16 MB
    bf16* vbf = (bf16*)(ws + 104 * MB);  // 16 MB
    bf16* gbf = (bf16*)(ws + 120 * MB);  // 16 MB  sigmoid gate
    bf16* abf = (bf16*)(ws + 136 * MB);  // 16 MB  attention out (pre-Wo)
    bf16* vtr = cbf;                     // V transposed [b][d][t], reuses cross slot (dead after V GEMM)
    bf16* pbf = qbf;                     // attn @ Wo + bo, reuses q slot (q dead by then)

    convert_bf16_kernel<<<8192, 256, 0, stream>>>(hidden, hbf);
    convert_bf16_kernel<<<8192, 256, 0, stream>>>(cross, cbf);
    const dim3 tg(64, 64);
    transpose_convert_kernel<<<tg, 256, 0, stream>>>(Wq, WqT);
    transpose_convert_kernel<<<tg, 256, 0, stream>>>(Wk, WkT);
    transpose_convert_kernel<<<tg, 256, 0, stream>>>(Wv, WvT);
    transpose_convert_kernel<<<tg, 256, 0, stream>>>(Wo, WoT);
    transpose_convert_kernel<<<tg, 256, 0, stream>>>(Wg, WgT);
    const dim3 gg(MROWS / 128, HID / 128);   // 32 x 16
    gemm_bt_kernel<false><<<gg, 256, 0, stream>>>(hbf, WqT, bq, qbf);
    gemm_bt_kernel<false><<<gg, 256, 0, stream>>>(cbf, WkT, bk, kbf);
    gemm_bt_kernel<false><<<gg, 256, 0, stream>>>(cbf, WvT, bv, vbf);
    gemm_bt_kernel<true ><<<gg, 256, 0, stream>>>(hbf, WgT, bg, gbf);
    transpose_v_kernel<<<dim3(64, 64, 2), 256, 0, stream>>>(vbf, vtr);
    attention_mfma_kernel<<<dim3(32, 32), 256, 0, stream>>>(qbf, kbf, vtr, abf);
    gemm_bt_kernel<false><<<gg, 256, 0, stream>>>(abf, WoT, bo, pbf);
    ln_kernel<<<MROWS, 256, 0, stream>>>(hidden, gbf, pbf, gamma, beta, out);
}